// Round 21
// baseline (64.141 us; speedup 1.0000x reference)
//
#include <hip/hip_runtime.h>

typedef unsigned short ushort_t;
typedef __attribute__((ext_vector_type(8))) __bf16 bf16x8;
typedef __attribute__((ext_vector_type(4))) float f32x4;
typedef __attribute__((ext_vector_type(4))) unsigned int u32x4;
typedef __attribute__((ext_vector_type(8))) unsigned short u16x8;

#define NQ 8192
#define NK 8192
#define DD 256
#define NSPLIT 8
#define SEG (NK / NSPLIT)   // 1024 K-rows per split
#define KBLK 64             // K rows staged in LDS per tile (32 KB)
#define NT (SEG / KBLK)     // 16 tiles per block
#define LOG2E 1.4426950408889634f
#define LN2 0.6931471805599453f

using gptr_t = const __attribute__((address_space(1))) void*;
using lptr_t = __attribute__((address_space(3))) void*;

__device__ __forceinline__ float fexp2(float x) { return __builtin_amdgcn_exp2f(x); }
__device__ __forceinline__ float flog2(float x) { return __builtin_amdgcn_logf(x); }

// round-to-nearest-even fp32 -> bf16
__device__ __forceinline__ ushort_t f2bf(float f) {
  unsigned int u = __builtin_bit_cast(unsigned int, f);
  unsigned int r = 0x7FFFu + ((u >> 16) & 1u);
  return (ushort_t)((u + r) >> 16);
}

// ---------------------------------------------------------------------------
// Kernel 1: projections OUT_bf16[8192x256] = X_fp32 @ W, transpose FUSED
// (R15-proven).  grid (128, 2, 4).
// ---------------------------------------------------------------------------
__global__ __launch_bounds__(256) void proj_kernel(
    const float* __restrict__ xq, const float* __restrict__ xk,
    const float* __restrict__ Wq, const float* __restrict__ Wk,
    ushort_t* __restrict__ Qb, ushort_t* __restrict__ Kb) {
  __shared__ __align__(16) char wt_lds[64 * 512];  // 32 KB
  const float* X = (blockIdx.y == 0) ? xq : xk;
  const float* W = (blockIdx.y == 0) ? Wq : Wk;
  ushort_t* OUT = (blockIdx.y == 0) ? Qb : Kb;
  const float scale = (blockIdx.y == 0) ? LOG2E : 1.0f;

  const int tid = threadIdx.x;
  const int w = tid >> 6, lane = tid & 63;
  const int g = lane >> 4, c = lane & 15;
  const int rbase = blockIdx.x * 64 + w * 16;
  const int ctbase = blockIdx.z * 4;

  {
    const int n_ = tid & 63;
    const int kb = (tid >> 6) * 2;
    const int nglob = blockIdx.z * 64 + n_;
#pragma unroll
    for (int i = 0; i < 32; ++i) {
      int k = i * 8 + kb;
      float w0 = W[(size_t)k * 256 + nglob];
      float w1 = W[(size_t)(k + 1) * 256 + nglob];
      unsigned int pk = (unsigned int)f2bf(w0) | ((unsigned int)f2bf(w1) << 16);
      int ch = i ^ (n_ & 7);
      *reinterpret_cast<unsigned int*>(&wt_lds[n_ * 512 + ch * 16 + (k & 7) * 2]) = pk;
    }
  }

  bf16x8 a[8];
#pragma unroll
  for (int kk = 0; kk < 8; ++kk) {
    const f32x4* px =
        reinterpret_cast<const f32x4*>(X + (size_t)(rbase + c) * DD + kk * 32 + g * 8);
    f32x4 x0 = px[0], x1 = px[1];
    u16x8 v;
#pragma unroll
    for (int j = 0; j < 4; ++j) { v[j] = f2bf(x0[j]); v[4 + j] = f2bf(x1[j]); }
    a[kk] = __builtin_bit_cast(bf16x8, v);
  }
  __syncthreads();

#pragma unroll
  for (int ct0 = 0; ct0 < 4; ++ct0) {
    const int jrl = ct0 * 16 + c;
    f32x4 acc = {0.f, 0.f, 0.f, 0.f};
#pragma unroll
    for (int kk = 0; kk < 8; ++kk) {
      int ch = (kk * 4 + g) ^ (c & 7);
      bf16x8 b = *reinterpret_cast<const bf16x8*>(&wt_lds[jrl * 512 + ch * 16]);
      acc = __builtin_amdgcn_mfma_f32_16x16x32_bf16(a[kk], b, acc, 0, 0, 0);
    }
    int ct = ctbase + ct0;
#pragma unroll
    for (int r = 0; r < 4; ++r)
      OUT[(size_t)(rbase + g * 4 + r) * DD + ct * 16 + c] = f2bf(acc[r] * scale);
  }
}

// ---------------------------------------------------------------------------
// Kernel 2: flash-style scores + online base-2 logsumexp partials.
// R13/R15-proven 2-phase structure (44.0 us, absmax 0) + R21's mechanism:
// ANTI-PHASE STAGGER.  Measured: wall 106k cyc/CU ~= LDS 65k + MFMA 40k
// fully SERIALIZED -- the 2 blocks/CU are frequency-locked (identical phase
// lengths, same start) so both sit in the same phase and contend for the
// same pipe.  Odd blocks sleep ~3300 cyc (half a tile period) at entry ->
// stable phase offset -> block A's MFMA overlaps block B's LDS/stage.
// setprio(1) around the MFMA cluster complements it (the MFMA-phase block
// wins arbitration once phases differ; alone it was null, R19).
// ---------------------------------------------------------------------------
__global__ __launch_bounds__(256, 2) void scores_lse_kernel(
    const ushort_t* __restrict__ Qb, const ushort_t* __restrict__ Kb,
    float* __restrict__ pm, float* __restrict__ ps) {
  __shared__ __align__(128) char smem[2][KBLK * 512];  // 64 KB
  const int tid = threadIdx.x;
  const int w = tid >> 6, lane = tid & 63;
  const int g = lane >> 4, c = lane & 15;
  const int qw = blockIdx.x * 128 + w * 32;
  const int j0 = blockIdx.y * SEG;

  // anti-phase stagger: odd blocks start ~half a tile period late
  if (blockIdx.x & 1) {
    asm volatile("s_sleep 52" :::);
  }

  // A-frags: 2 row-tiles x 8 k-steps (64 VGPRs, resident whole kernel).
  bf16x8 a[2][8];
#pragma unroll
  for (int rt = 0; rt < 2; ++rt)
#pragma unroll
    for (int kk = 0; kk < 8; ++kk) {
      u32x4 v = *reinterpret_cast<const u32x4*>(
          Qb + (size_t)(qw + rt * 16 + c) * DD + kk * 32 + g * 8);
      a[rt][kk] = __builtin_bit_cast(bf16x8, v);
    }
  asm volatile("s_waitcnt vmcnt(0)" ::: "memory");

  // hoisted per-lane ds_read bases (even/odd kk parity; R7 derivation)
  const int c2 = (c >> 2) & 1;
  const int lbase = c * 512 + ((g ^ (c & 3)) << 4);
  const int base_e = lbase + c2 * 64;
  const int base_o = lbase - c2 * 64;

  float m[2][4], s[2][4];
#pragma unroll
  for (int rt = 0; rt < 2; ++rt)
#pragma unroll
    for (int r = 0; r < 4; ++r) { m[rt][r] = -3.4e38f; s[rt][r] = 0.f; }

  f32x4 accA[2][4], accB[2][4];

  // stage tile t (64 rows, 32 KB): 4 waves x 8 gload_lds(16B) each.
  // LDS[row][ch] = K[row][ch^(row&7)] via swizzled GLOBAL source.
#define STAGE(buf, t)                                                          \
  do {                                                                         \
    const char* kbase_ = (const char*)(Kb + (size_t)(j0 + (t) * KBLK) * DD);   \
    _Pragma("unroll") for (int i_ = 0; i_ < 8; ++i_) {                         \
      int L_ = (w * 8 + i_) * 64 + lane;                                       \
      int row_ = L_ >> 5, ch_ = L_ & 31;                                       \
      const char* src_ = kbase_ + row_ * 512 + ((ch_ ^ (row_ & 7)) * 16);      \
      char* dst_ = &smem[buf][L_ * 16];                                        \
      __builtin_amdgcn_global_load_lds((gptr_t)src_, (lptr_t)dst_, 16, 0, 0);  \
    }                                                                          \
  } while (0)

  // reads+MFMA of one tile into acc set C (zero-init inside); MFMA cluster
  // wrapped in setprio(1)/(0).
#define MFMA_TILE(buf, C)                                                      \
  do {                                                                         \
    const char* se_ = &smem[buf][0] + base_e;                                  \
    const char* so_ = &smem[buf][0] + base_o;                                  \
    _Pragma("unroll") for (int rt_ = 0; rt_ < 2; ++rt_)                        \
    _Pragma("unroll") for (int jt_ = 0; jt_ < 4; ++jt_)                        \
        C[rt_][jt_] = (f32x4){0.f, 0.f, 0.f, 0.f};                             \
    __builtin_amdgcn_s_setprio(1);                                             \
    _Pragma("unroll") for (int kk_ = 0; kk_ < 8; kk_ += 2) {                   \
      _Pragma("unroll") for (int jt_ = 0; jt_ < 4; ++jt_) {                    \
        bf16x8 be_ = *reinterpret_cast<const bf16x8*>(se_ + jt_ * 8192 + kk_ * 64); \
        bf16x8 bo_ = *reinterpret_cast<const bf16x8*>(so_ + jt_ * 8192 + (kk_ + 1) * 64); \
        C[0][jt_] = __builtin_amdgcn_mfma_f32_16x16x32_bf16(a[0][kk_], be_, C[0][jt_], 0, 0, 0); \
        C[1][jt_] = __builtin_amdgcn_mfma_f32_16x16x32_bf16(a[1][kk_], be_, C[1][jt_], 0, 0, 0); \
        C[0][jt_] = __builtin_amdgcn_mfma_f32_16x16x32_bf16(a[0][kk_ + 1], bo_, C[0][jt_], 0, 0, 0); \
        C[1][jt_] = __builtin_amdgcn_mfma_f32_16x16x32_bf16(a[1][kk_ + 1], bo_, C[1][jt_], 0, 0, 0); \
      }                                                                        \
    }                                                                          \
    __builtin_amdgcn_s_setprio(0);                                             \
  } while (0)

  // branchless grouped online-lse fold of acc set F (one basic block)
#define FOLD(F)                                                                \
  do {                                                                         \
    _Pragma("unroll") for (int rt_ = 0; rt_ < 2; ++rt_)                        \
    _Pragma("unroll") for (int r_ = 0; r_ < 4; ++r_) {                         \
      float v0_ = F[rt_][0][r_], v1_ = F[rt_][1][r_];                          \
      float v2_ = F[rt_][2][r_], v3_ = F[rt_][3][r_];                          \
      float tm_ = fmaxf(fmaxf(v0_, v1_), fmaxf(v2_, v3_));                     \
      float mo_ = m[rt_][r_];                                                  \
      float mn_ = fmaxf(mo_, tm_);                                             \
      float sc_ = fexp2(mo_ - mn_);                                            \
      s[rt_][r_] = s[rt_][r_] * sc_ +                                          \
                   (fexp2(v0_ - mn_) + fexp2(v1_ - mn_) +                      \
                    fexp2(v2_ - mn_) + fexp2(v3_ - mn_));                      \
      m[rt_][r_] = mn_;                                                        \
    }                                                                          \
  } while (0)

  // ---- prologue: tile 0 -> accA (no fold yet)
  STAGE(0, 0);
  STAGE(1, 1);
  asm volatile("s_waitcnt vmcnt(8)" ::: "memory");
  __builtin_amdgcn_s_barrier();
  MFMA_TILE(0, accA);
  asm volatile("s_waitcnt lgkmcnt(0)" ::: "memory");
  __builtin_amdgcn_s_barrier();

  // ---- main loop: tiles 1..NT-2 in pairs (NT=16: tt = 1,3,...,13)
#pragma unroll 1
  for (int tt = 1; tt + 1 < NT; tt += 2) {
    // tile tt (buf1) -> accB; fold accA (tile tt-1) overlaps the vmcnt wait
    STAGE(0, tt + 1);
    FOLD(accA);
    asm volatile("s_waitcnt vmcnt(8)" ::: "memory");
    __builtin_amdgcn_s_barrier();
    MFMA_TILE(1, accB);
    asm volatile("s_waitcnt lgkmcnt(0)" ::: "memory");
    __builtin_amdgcn_s_barrier();

    // tile tt+1 (buf0) -> accA; fold accB (tile tt)
    STAGE(1, tt + 2);
    FOLD(accB);
    asm volatile("s_waitcnt vmcnt(8)" ::: "memory");
    __builtin_amdgcn_s_barrier();
    MFMA_TILE(0, accA);
    asm volatile("s_waitcnt lgkmcnt(0)" ::: "memory");
    __builtin_amdgcn_s_barrier();
  }

  // ---- epilogue: tile NT-1 (buf1) -> accB; folds of last two acc sets
  FOLD(accA);
  asm volatile("s_waitcnt vmcnt(0)" ::: "memory");
  __builtin_amdgcn_s_barrier();
  MFMA_TILE(1, accB);
  FOLD(accB);
#undef STAGE
#undef MFMA_TILE
#undef FOLD

  // merge the 16 lanes of each group (each held a 4-col-stride slice)
#pragma unroll
  for (int rt = 0; rt < 2; ++rt)
#pragma unroll
    for (int r = 0; r < 4; ++r) {
      float M = m[rt][r], S = s[rt][r];
#pragma unroll
      for (int off = 1; off < 16; off <<= 1) {
        float Mo = __shfl_xor(M, off);
        float So = __shfl_xor(S, off);
        float Mn = fmaxf(M, Mo);
        S = S * fexp2(M - Mn) + So * fexp2(Mo - Mn);
        M = Mn;
      }
      if (c == 0) {
        int row = qw + rt * 16 + g * 4 + r;
        pm[blockIdx.y * NQ + row] = M;
        ps[blockIdx.y * NQ + row] = S;
      }
    }
}

// ---------------------------------------------------------------------------
// Kernel 3: per-row lse (base-2 partials -> natural), block-sum -> part[64]
// ---------------------------------------------------------------------------
__global__ __launch_bounds__(128) void finalize1_kernel(
    const float* __restrict__ pm, const float* __restrict__ ps,
    float* __restrict__ part) {
  const int tid = threadIdx.x;
  const int row = blockIdx.x * 128 + tid;
  float M = -3.4e38f;
#pragma unroll
  for (int k = 0; k < NSPLIT; ++k) M = fmaxf(M, pm[k * NQ + row]);
  float S = 0.f;
#pragma unroll
  for (int k = 0; k < NSPLIT; ++k) S += ps[k * NQ + row] * fexp2(pm[k * NQ + row] - M);
  float v = LN2 * (M + flog2(S));

  __shared__ float red[128];
  red[tid] = v;
  __syncthreads();
#pragma unroll
  for (int st = 64; st > 0; st >>= 1) {
    if (tid < st) red[tid] += red[tid + st];
    __syncthreads();
  }
  if (tid == 0) part[blockIdx.x] = red[0];
}

// ---------------------------------------------------------------------------
// Kernel 4: sum 64 partials, negate.
// ---------------------------------------------------------------------------
__global__ __launch_bounds__(64) void finalize2_kernel(
    const float* __restrict__ part, float* __restrict__ out) {
  const int lane = threadIdx.x;
  float v = part[lane];
#pragma unroll
  for (int off = 1; off < 64; off <<= 1) v += __shfl_xor(v, off);
  if (lane == 0) out[0] = -v;
}

// ---------------------------------------------------------------------------
extern "C" void kernel_launch(void* const* d_in, const int* in_sizes, int n_in,
                              void* d_out, int out_size, void* d_ws, size_t ws_size,
                              hipStream_t stream) {
  const float* xq = (const float*)d_in[0];
  const float* xk = (const float*)d_in[1];
  const float* Wq = (const float*)d_in[2];
  const float* Wk = (const float*)d_in[3];

  char* ws = (char*)d_ws;
  // ws: Qb 4MB | Kb 4MB | pm 256KB | ps 256KB | part 256B
  ushort_t* Qb = (ushort_t*)(ws);
  ushort_t* Kb = (ushort_t*)(ws + (size_t)NQ * DD * 2);
  float* pm = (float*)(ws + (size_t)(NQ + NK) * DD * 2);
  float* ps = pm + (size_t)NSPLIT * NQ;
  float* part = ps + (size_t)NSPLIT * NQ;

  hipLaunchKernelGGL(proj_kernel, dim3(128, 2, 4), dim3(256), 0, stream,
                     xq, xk, Wq, Wk, Qb, Kb);
  hipLaunchKernelGGL(scores_lse_kernel, dim3(NQ / 128, NSPLIT), dim3(256), 0, stream,
                     Qb, Kb, pm, ps);
  hipLaunchKernelGGL(finalize1_kernel, dim3(64), dim3(128), 0, stream, pm, ps, part);
  hipLaunchKernelGGL(finalize2_kernel, dim3(1), dim3(64), 0, stream, part, (float*)d_out);
}

// Round 22
// 60.810 us; speedup vs baseline: 1.0548x; 1.0548x over previous
//
#include <hip/hip_runtime.h>

typedef unsigned short ushort_t;
typedef __attribute__((ext_vector_type(8))) __bf16 bf16x8;
typedef __attribute__((ext_vector_type(4))) float f32x4;
typedef __attribute__((ext_vector_type(4))) unsigned int u32x4;
typedef __attribute__((ext_vector_type(8))) unsigned short u16x8;

#define NQ 8192
#define NK 8192
#define DD 256
#define NSPLIT 8
#define SEG (NK / NSPLIT)   // 1024 K-rows per split
#define KBLK 64             // K rows staged in LDS per tile (32 KB)
#define NT (SEG / KBLK)     // 16 tiles per block
#define LOG2E 1.4426950408889634f
#define LN2 0.6931471805599453f

using gptr_t = const __attribute__((address_space(1))) void*;
using lptr_t = __attribute__((address_space(3))) void*;

__device__ __forceinline__ float fexp2(float x) { return __builtin_amdgcn_exp2f(x); }
__device__ __forceinline__ float flog2(float x) { return __builtin_amdgcn_logf(x); }

// round-to-nearest-even fp32 -> bf16
__device__ __forceinline__ ushort_t f2bf(float f) {
  unsigned int u = __builtin_bit_cast(unsigned int, f);
  unsigned int r = 0x7FFFu + ((u >> 16) & 1u);
  return (ushort_t)((u + r) >> 16);
}

// ---------------------------------------------------------------------------
// Kernel 1: projections OUT_bf16[8192x256] = X_fp32 @ W, transpose FUSED
// (R15-proven: -14 us vs separate transpose).  grid (128, 2, 4).
// ---------------------------------------------------------------------------
__global__ __launch_bounds__(256) void proj_kernel(
    const float* __restrict__ xq, const float* __restrict__ xk,
    const float* __restrict__ Wq, const float* __restrict__ Wk,
    ushort_t* __restrict__ Qb, ushort_t* __restrict__ Kb) {
  __shared__ __align__(16) char wt_lds[64 * 512];  // 32 KB
  const float* X = (blockIdx.y == 0) ? xq : xk;
  const float* W = (blockIdx.y == 0) ? Wq : Wk;
  ushort_t* OUT = (blockIdx.y == 0) ? Qb : Kb;
  const float scale = (blockIdx.y == 0) ? LOG2E : 1.0f;

  const int tid = threadIdx.x;
  const int w = tid >> 6, lane = tid & 63;
  const int g = lane >> 4, c = lane & 15;
  const int rbase = blockIdx.x * 64 + w * 16;
  const int ctbase = blockIdx.z * 4;

  {
    const int n_ = tid & 63;
    const int kb = (tid >> 6) * 2;
    const int nglob = blockIdx.z * 64 + n_;
#pragma unroll
    for (int i = 0; i < 32; ++i) {
      int k = i * 8 + kb;
      float w0 = W[(size_t)k * 256 + nglob];
      float w1 = W[(size_t)(k + 1) * 256 + nglob];
      unsigned int pk = (unsigned int)f2bf(w0) | ((unsigned int)f2bf(w1) << 16);
      int ch = i ^ (n_ & 7);
      *reinterpret_cast<unsigned int*>(&wt_lds[n_ * 512 + ch * 16 + (k & 7) * 2]) = pk;
    }
  }

  bf16x8 a[8];
#pragma unroll
  for (int kk = 0; kk < 8; ++kk) {
    const f32x4* px =
        reinterpret_cast<const f32x4*>(X + (size_t)(rbase + c) * DD + kk * 32 + g * 8);
    f32x4 x0 = px[0], x1 = px[1];
    u16x8 v;
#pragma unroll
    for (int j = 0; j < 4; ++j) { v[j] = f2bf(x0[j]); v[4 + j] = f2bf(x1[j]); }
    a[kk] = __builtin_bit_cast(bf16x8, v);
  }
  __syncthreads();

#pragma unroll
  for (int ct0 = 0; ct0 < 4; ++ct0) {
    const int jrl = ct0 * 16 + c;
    f32x4 acc = {0.f, 0.f, 0.f, 0.f};
#pragma unroll
    for (int kk = 0; kk < 8; ++kk) {
      int ch = (kk * 4 + g) ^ (c & 7);
      bf16x8 b = *reinterpret_cast<const bf16x8*>(&wt_lds[jrl * 512 + ch * 16]);
      acc = __builtin_amdgcn_mfma_f32_16x16x32_bf16(a[kk], b, acc, 0, 0, 0);
    }
    int ct = ctbase + ct0;
#pragma unroll
    for (int r = 0; r < 4; ++r)
      OUT[(size_t)(rbase + g * 4 + r) * DD + ct * 16 + c] = f2bf(acc[r] * scale);
  }
}

// ---------------------------------------------------------------------------
// Kernel 2: flash-style scores + online base-2 logsumexp partials.
// R13/R15-proven structure (44.0 us, absmax 0): grid (NQ/128, NSPLIT),
// 4 waves x 32 Q-rows, K tile [64x256] bf16 double-buffered, gload_lds(16)
// + XOR chunk-swizzle on the GLOBAL source, counted vmcnt(8), raw barriers
// (no drain), fold overlapping the vmcnt wait.
// PLATEAU NOTE (R16-R21): ten schedule variants (phase-split, setprio,
// stagger, fold placement, barrier thinning, occupancy changes, AGPR
// pinning) all measured 44-46.5 us.  Wall = LDS ~65k cyc/CU + MFMA ~40k,
// serialized; perfect-overlap floor would be ~17 us but no HIP-source
// mechanism tested here breaks the phase lock.  Stagger/setprio removed
// (measured <=0).
// ---------------------------------------------------------------------------
__global__ __launch_bounds__(256, 2) void scores_lse_kernel(
    const ushort_t* __restrict__ Qb, const ushort_t* __restrict__ Kb,
    float* __restrict__ pm, float* __restrict__ ps) {
  __shared__ __align__(128) char smem[2][KBLK * 512];  // 64 KB
  const int tid = threadIdx.x;
  const int w = tid >> 6, lane = tid & 63;
  const int g = lane >> 4, c = lane & 15;
  const int qw = blockIdx.x * 128 + w * 32;
  const int j0 = blockIdx.y * SEG;

  // A-frags: 2 row-tiles x 8 k-steps (64 VGPRs, resident whole kernel).
  bf16x8 a[2][8];
#pragma unroll
  for (int rt = 0; rt < 2; ++rt)
#pragma unroll
    for (int kk = 0; kk < 8; ++kk) {
      u32x4 v = *reinterpret_cast<const u32x4*>(
          Qb + (size_t)(qw + rt * 16 + c) * DD + kk * 32 + g * 8);
      a[rt][kk] = __builtin_bit_cast(bf16x8, v);
    }
  asm volatile("s_waitcnt vmcnt(0)" ::: "memory");

  // hoisted per-lane ds_read bases (even/odd kk parity; R7 derivation)
  const int c2 = (c >> 2) & 1;
  const int lbase = c * 512 + ((g ^ (c & 3)) << 4);
  const int base_e = lbase + c2 * 64;
  const int base_o = lbase - c2 * 64;

  float m[2][4], s[2][4];
#pragma unroll
  for (int rt = 0; rt < 2; ++rt)
#pragma unroll
    for (int r = 0; r < 4; ++r) { m[rt][r] = -3.4e38f; s[rt][r] = 0.f; }

  f32x4 accA[2][4], accB[2][4];

  // stage tile t (64 rows, 32 KB): 4 waves x 8 gload_lds(16B) each.
  // LDS[row][ch] = K[row][ch^(row&7)] via swizzled GLOBAL source.
#define STAGE(buf, t)                                                          \
  do {                                                                         \
    const char* kbase_ = (const char*)(Kb + (size_t)(j0 + (t) * KBLK) * DD);   \
    _Pragma("unroll") for (int i_ = 0; i_ < 8; ++i_) {                         \
      int L_ = (w * 8 + i_) * 64 + lane;                                       \
      int row_ = L_ >> 5, ch_ = L_ & 31;                                       \
      const char* src_ = kbase_ + row_ * 512 + ((ch_ ^ (row_ & 7)) * 16);      \
      char* dst_ = &smem[buf][L_ * 16];                                        \
      __builtin_amdgcn_global_load_lds((gptr_t)src_, (lptr_t)dst_, 16, 0, 0);  \
    }                                                                          \
  } while (0)

  // reads+MFMA of one tile into acc set C (zero-init inside)
#define MFMA_TILE(buf, C)                                                      \
  do {                                                                         \
    const char* se_ = &smem[buf][0] + base_e;                                  \
    const char* so_ = &smem[buf][0] + base_o;                                  \
    _Pragma("unroll") for (int rt_ = 0; rt_ < 2; ++rt_)                        \
    _Pragma("unroll") for (int jt_ = 0; jt_ < 4; ++jt_)                        \
        C[rt_][jt_] = (f32x4){0.f, 0.f, 0.f, 0.f};                             \
    _Pragma("unroll") for (int kk_ = 0; kk_ < 8; kk_ += 2) {                   \
      _Pragma("unroll") for (int jt_ = 0; jt_ < 4; ++jt_) {                    \
        bf16x8 be_ = *reinterpret_cast<const bf16x8*>(se_ + jt_ * 8192 + kk_ * 64); \
        bf16x8 bo_ = *reinterpret_cast<const bf16x8*>(so_ + jt_ * 8192 + (kk_ + 1) * 64); \
        C[0][jt_] = __builtin_amdgcn_mfma_f32_16x16x32_bf16(a[0][kk_], be_, C[0][jt_], 0, 0, 0); \
        C[1][jt_] = __builtin_amdgcn_mfma_f32_16x16x32_bf16(a[1][kk_], be_, C[1][jt_], 0, 0, 0); \
        C[0][jt_] = __builtin_amdgcn_mfma_f32_16x16x32_bf16(a[0][kk_ + 1], bo_, C[0][jt_], 0, 0, 0); \
        C[1][jt_] = __builtin_amdgcn_mfma_f32_16x16x32_bf16(a[1][kk_ + 1], bo_, C[1][jt_], 0, 0, 0); \
      }                                                                        \
    }                                                                          \
  } while (0)

  // branchless grouped online-lse fold of acc set F (one basic block)
#define FOLD(F)                                                                \
  do {                                                                         \
    _Pragma("unroll") for (int rt_ = 0; rt_ < 2; ++rt_)                        \
    _Pragma("unroll") for (int r_ = 0; r_ < 4; ++r_) {                         \
      float v0_ = F[rt_][0][r_], v1_ = F[rt_][1][r_];                          \
      float v2_ = F[rt_][2][r_], v3_ = F[rt_][3][r_];                          \
      float tm_ = fmaxf(fmaxf(v0_, v1_), fmaxf(v2_, v3_));                     \
      float mo_ = m[rt_][r_];                                                  \
      float mn_ = fmaxf(mo_, tm_);                                             \
      float sc_ = fexp2(mo_ - mn_);                                            \
      s[rt_][r_] = s[rt_][r_] * sc_ +                                          \
                   (fexp2(v0_ - mn_) + fexp2(v1_ - mn_) +                      \
                    fexp2(v2_ - mn_) + fexp2(v3_ - mn_));                      \
      m[rt_][r_] = mn_;                                                        \
    }                                                                          \
  } while (0)

  // ---- prologue: tile 0 -> accA (no fold yet)
  STAGE(0, 0);
  STAGE(1, 1);
  asm volatile("s_waitcnt vmcnt(8)" ::: "memory");
  __builtin_amdgcn_s_barrier();
  MFMA_TILE(0, accA);
  asm volatile("s_waitcnt lgkmcnt(0)" ::: "memory");
  __builtin_amdgcn_s_barrier();

  // ---- main loop: tiles 1..NT-2 in pairs (NT=16: tt = 1,3,...,13)
#pragma unroll 1
  for (int tt = 1; tt + 1 < NT; tt += 2) {
    // tile tt (buf1) -> accB; fold accA (tile tt-1) overlaps the vmcnt wait
    STAGE(0, tt + 1);
    FOLD(accA);
    asm volatile("s_waitcnt vmcnt(8)" ::: "memory");
    __builtin_amdgcn_s_barrier();
    MFMA_TILE(1, accB);
    asm volatile("s_waitcnt lgkmcnt(0)" ::: "memory");
    __builtin_amdgcn_s_barrier();

    // tile tt+1 (buf0) -> accA; fold accB (tile tt)
    STAGE(1, tt + 2);
    FOLD(accB);
    asm volatile("s_waitcnt vmcnt(8)" ::: "memory");
    __builtin_amdgcn_s_barrier();
    MFMA_TILE(0, accA);
    asm volatile("s_waitcnt lgkmcnt(0)" ::: "memory");
    __builtin_amdgcn_s_barrier();
  }

  // ---- epilogue: tile NT-1 (buf1) -> accB; folds of last two acc sets
  FOLD(accA);
  asm volatile("s_waitcnt vmcnt(0)" ::: "memory");
  __builtin_amdgcn_s_barrier();
  MFMA_TILE(1, accB);
  FOLD(accB);
#undef STAGE
#undef MFMA_TILE
#undef FOLD

  // merge the 16 lanes of each group (each held a 4-col-stride slice)
#pragma unroll
  for (int rt = 0; rt < 2; ++rt)
#pragma unroll
    for (int r = 0; r < 4; ++r) {
      float M = m[rt][r], S = s[rt][r];
#pragma unroll
      for (int off = 1; off < 16; off <<= 1) {
        float Mo = __shfl_xor(M, off);
        float So = __shfl_xor(S, off);
        float Mn = fmaxf(M, Mo);
        S = S * fexp2(M - Mn) + So * fexp2(Mo - Mn);
        M = Mn;
      }
      if (c == 0) {
        int row = qw + rt * 16 + g * 4 + r;
        pm[blockIdx.y * NQ + row] = M;
        ps[blockIdx.y * NQ + row] = S;
      }
    }
}

// ---------------------------------------------------------------------------
// Kernel 3: per-row lse (base-2 partials -> natural), block-sum -> part[64]
// ---------------------------------------------------------------------------
__global__ __launch_bounds__(128) void finalize1_kernel(
    const float* __restrict__ pm, const float* __restrict__ ps,
    float* __restrict__ part) {
  const int tid = threadIdx.x;
  const int row = blockIdx.x * 128 + tid;
  float M = -3.4e38f;
#pragma unroll
  for (int k = 0; k < NSPLIT; ++k) M = fmaxf(M, pm[k * NQ + row]);
  float S = 0.f;
#pragma unroll
  for (int k = 0; k < NSPLIT; ++k) S += ps[k * NQ + row] * fexp2(pm[k * NQ + row] - M);
  float v = LN2 * (M + flog2(S));

  __shared__ float red[128];
  red[tid] = v;
  __syncthreads();
#pragma unroll
  for (int st = 64; st > 0; st >>= 1) {
    if (tid < st) red[tid] += red[tid + st];
    __syncthreads();
  }
  if (tid == 0) part[blockIdx.x] = red[0];
}

// ---------------------------------------------------------------------------
// Kernel 4: sum 64 partials, negate.
// ---------------------------------------------------------------------------
__global__ __launch_bounds__(64) void finalize2_kernel(
    const float* __restrict__ part, float* __restrict__ out) {
  const int lane = threadIdx.x;
  float v = part[lane];
#pragma unroll
  for (int off = 1; off < 64; off <<= 1) v += __shfl_xor(v, off);
  if (lane == 0) out[0] = -v;
}

// ---------------------------------------------------------------------------
extern "C" void kernel_launch(void* const* d_in, const int* in_sizes, int n_in,
                              void* d_out, int out_size, void* d_ws, size_t ws_size,
                              hipStream_t stream) {
  const float* xq = (const float*)d_in[0];
  const float* xk = (const float*)d_in[1];
  const float* Wq = (const float*)d_in[2];
  const float* Wk = (const float*)d_in[3];

  char* ws = (char*)d_ws;
  // ws: Qb 4MB | Kb 4MB | pm 256KB | ps 256KB | part 256B
  ushort_t* Qb = (ushort_t*)(ws);
  ushort_t* Kb = (ushort_t*)(ws + (size_t)NQ * DD * 2);
  float* pm = (float*)(ws + (size_t)(NQ + NK) * DD * 2);
  float* ps = pm + (size_t)NSPLIT * NQ;
  float* part = ps + (size_t)NSPLIT * NQ;

  hipLaunchKernelGGL(proj_kernel, dim3(128, 2, 4), dim3(256), 0, stream,
                     xq, xk, Wq, Wk, Qb, Kb);
  hipLaunchKernelGGL(scores_lse_kernel, dim3(NQ / 128, NSPLIT), dim3(256), 0, stream,
                     Qb, Kb, pm, ps);
  hipLaunchKernelGGL(finalize1_kernel, dim3(64), dim3(128), 0, stream, pm, ps, part);
  hipLaunchKernelGGL(finalize2_kernel, dim3(1), dim3(64), 0, stream, part, (float*)d_out);
}

// Round 23
// 56.672 us; speedup vs baseline: 1.1318x; 1.0730x over previous
//
#include <hip/hip_runtime.h>

typedef unsigned short ushort_t;
typedef unsigned char uchar_t;
typedef __attribute__((ext_vector_type(8))) __bf16 bf16x8;
typedef __attribute__((ext_vector_type(4))) float f32x4;
typedef __attribute__((ext_vector_type(2))) unsigned int u32x2;
typedef __attribute__((ext_vector_type(4))) unsigned int u32x4;
typedef __attribute__((ext_vector_type(8))) unsigned short u16x8;

#define NQ 8192
#define NK 8192
#define DD 256
#define NSPLIT 8
#define SEG (NK / NSPLIT)   // 1024 K-rows per split
#define KBLK 64             // K rows staged in LDS per tile (16 KB in fp8)
#define NT (SEG / KBLK)     // 16 tiles per block
#define LOG2E 1.4426950408889634f
#define LN2 0.6931471805599453f

using gptr_t = const __attribute__((address_space(1))) void*;
using lptr_t = __attribute__((address_space(3))) void*;

__device__ __forceinline__ float fexp2(float x) { return __builtin_amdgcn_exp2f(x); }
__device__ __forceinline__ float flog2(float x) { return __builtin_amdgcn_logf(x); }

// round-to-nearest-even fp32 -> bf16
__device__ __forceinline__ ushort_t f2bf(float f) {
  unsigned int u = __builtin_bit_cast(unsigned int, f);
  unsigned int r = 0x7FFFu + ((u >> 16) & 1u);
  return (ushort_t)((u + r) >> 16);
}

// fp32 -> fp8 e4m3fn (OCP), RTN, clamp to +-448, flush denormals to 0.
// Inputs here are |v| <~ 140 (scores path), well inside normal range.
__device__ __forceinline__ uchar_t f2fp8(float f) {
  unsigned int u = __builtin_bit_cast(unsigned int, f);
  unsigned int sgn = (u >> 24) & 0x80u;
  int e = (int)((u >> 23) & 0xFFu) - 127;
  unsigned int mant = (u >> 20) & 0x7u;
  unsigned int rest = u & 0xFFFFFu;
  if (e < -6) return (uchar_t)sgn;               // flush tiny/denormal to 0
  if (e > 8) return (uchar_t)(sgn | 0x7Eu);      // clamp to 448
  unsigned int enc = ((unsigned int)(e + 7) << 3) | mant;
  unsigned int rnd = (rest > 0x80000u) || (rest == 0x80000u && (mant & 1u));
  enc += rnd;                                    // carry into exponent is OK
  if (enc >= 0x7Fu) enc = 0x7Eu;                 // avoid NaN encoding
  return (uchar_t)(sgn | enc);
}

// ---------------------------------------------------------------------------
// Kernel 1: projections OUT_fp8[8192x256] = fp8(X_fp32 @ W), transpose FUSED
// (R15-proven bf16-MFMA internals; only the output format changed to fp8
// e4m3).  Q additionally scaled by log2(e).  grid (128, 2, 4).
// ---------------------------------------------------------------------------
__global__ __launch_bounds__(256) void proj_kernel(
    const float* __restrict__ xq, const float* __restrict__ xk,
    const float* __restrict__ Wq, const float* __restrict__ Wk,
    uchar_t* __restrict__ Qb, uchar_t* __restrict__ Kb) {
  __shared__ __align__(16) char wt_lds[64 * 512];  // 32 KB (bf16 W^T slice)
  const float* X = (blockIdx.y == 0) ? xq : xk;
  const float* W = (blockIdx.y == 0) ? Wq : Wk;
  uchar_t* OUT = (blockIdx.y == 0) ? Qb : Kb;
  const float scale = (blockIdx.y == 0) ? LOG2E : 1.0f;

  const int tid = threadIdx.x;
  const int w = tid >> 6, lane = tid & 63;
  const int g = lane >> 4, c = lane & 15;
  const int rbase = blockIdx.x * 64 + w * 16;
  const int ctbase = blockIdx.z * 4;

  {
    const int n_ = tid & 63;
    const int kb = (tid >> 6) * 2;
    const int nglob = blockIdx.z * 64 + n_;
#pragma unroll
    for (int i = 0; i < 32; ++i) {
      int k = i * 8 + kb;
      float w0 = W[(size_t)k * 256 + nglob];
      float w1 = W[(size_t)(k + 1) * 256 + nglob];
      unsigned int pk = (unsigned int)f2bf(w0) | ((unsigned int)f2bf(w1) << 16);
      int ch = i ^ (n_ & 7);
      *reinterpret_cast<unsigned int*>(&wt_lds[n_ * 512 + ch * 16 + (k & 7) * 2]) = pk;
    }
  }

  bf16x8 a[8];
#pragma unroll
  for (int kk = 0; kk < 8; ++kk) {
    const f32x4* px =
        reinterpret_cast<const f32x4*>(X + (size_t)(rbase + c) * DD + kk * 32 + g * 8);
    f32x4 x0 = px[0], x1 = px[1];
    u16x8 v;
#pragma unroll
    for (int j = 0; j < 4; ++j) { v[j] = f2bf(x0[j]); v[4 + j] = f2bf(x1[j]); }
    a[kk] = __builtin_bit_cast(bf16x8, v);
  }
  __syncthreads();

#pragma unroll
  for (int ct0 = 0; ct0 < 4; ++ct0) {
    const int jrl = ct0 * 16 + c;
    f32x4 acc = {0.f, 0.f, 0.f, 0.f};
#pragma unroll
    for (int kk = 0; kk < 8; ++kk) {
      int ch = (kk * 4 + g) ^ (c & 7);
      bf16x8 b = *reinterpret_cast<const bf16x8*>(&wt_lds[jrl * 512 + ch * 16]);
      acc = __builtin_amdgcn_mfma_f32_16x16x32_bf16(a[kk], b, acc, 0, 0, 0);
    }
    int ct = ctbase + ct0;
#pragma unroll
    for (int r = 0; r < 4; ++r)
      OUT[(size_t)(rbase + g * 4 + r) * DD + ct * 16 + c] = f2fp8(acc[r] * scale);
  }
}

// ---------------------------------------------------------------------------
// Kernel 2: flash-style scores + online base-2 logsumexp partials, FP8.
// R13/R15-proven sync skeleton (counted vmcnt, raw barriers, no drain,
// fold overlapping the vmcnt wait), with K/Q in fp8 e4m3:
//  - K tile is 64x256 BYTES = 16 KB (was 32 KB): LDS traffic HALVES (the
//    measured binding pipe, ~65k cyc/CU at bf16).
//  - B-frag reads are ds_read_b64 (8B/lane, one fp8-MFMA K=32 operand);
//    with the same chunk-XOR swizzle the bank pattern is exactly 2-way
//    (free, m136).
//  - mfma_f32_16x16x32_fp8_fp8: same MFMA count (64/wave/tile) at bf16 rate
//    (MFMA was not binding).
// ---------------------------------------------------------------------------
__global__ __launch_bounds__(256, 2) void scores_lse_kernel(
    const uchar_t* __restrict__ Qb, const uchar_t* __restrict__ Kb,
    float* __restrict__ pm, float* __restrict__ ps) {
  __shared__ __align__(128) char smem[2][KBLK * 256];  // 2 x 16 KB
  const int tid = threadIdx.x;
  const int w = tid >> 6, lane = tid & 63;
  const int g = lane >> 4, c = lane & 15;
  const int qw = blockIdx.x * 128 + w * 32;
  const int j0 = blockIdx.y * SEG;

  // A-frags: 2 row-tiles x 8 k-blocks, 8 fp8 bytes each (32 VGPRs total).
  u32x2 a[2][8];
#pragma unroll
  for (int rt = 0; rt < 2; ++rt)
#pragma unroll
    for (int kb = 0; kb < 8; ++kb)
      a[rt][kb] = *reinterpret_cast<const u32x2*>(
          Qb + (size_t)(qw + rt * 16 + c) * DD + kb * 32 + g * 8);
  asm volatile("s_waitcnt vmcnt(0)" ::: "memory");

  const int cx = c & 7;
  const int g2 = g >> 1;              // which 16B chunk half within the k-block pair
  const int g1o = (g & 1) * 8;        // byte offset within the 16B chunk
  const int rowb = c * 256 + g1o;     // per-lane row base (row = jt*16 + c)

  float m[2][4], s[2][4];
#pragma unroll
  for (int rt = 0; rt < 2; ++rt)
#pragma unroll
    for (int r = 0; r < 4; ++r) { m[rt][r] = -3.4e38f; s[rt][r] = 0.f; }

  f32x4 accA[2][4], accB[2][4];

  // stage tile t (64 rows x 256B = 16 KB): 4 waves x 4 gload_lds(16B).
  // LDS[row][ch] = K[row][ch^(row&7)] via swizzled GLOBAL source (16 chunks).
#define STAGE(buf, t)                                                          \
  do {                                                                         \
    const char* kbase_ = (const char*)(Kb + (size_t)(j0 + (t) * KBLK) * DD);   \
    _Pragma("unroll") for (int i_ = 0; i_ < 4; ++i_) {                         \
      int L_ = (w * 4 + i_) * 64 + lane;                                       \
      int row_ = L_ >> 4, ch_ = L_ & 15;                                       \
      const char* src_ = kbase_ + row_ * 256 + ((ch_ ^ (row_ & 7)) * 16);      \
      char* dst_ = &smem[buf][L_ * 16];                                        \
      __builtin_amdgcn_global_load_lds((gptr_t)src_, (lptr_t)dst_, 16, 0, 0);  \
    }                                                                          \
  } while (0)

  // reads+MFMA of one tile into acc set C (zero-init inside)
#define MFMA_TILE(buf, C)                                                      \
  do {                                                                         \
    const char* sb_ = &smem[buf][0] + rowb;                                    \
    _Pragma("unroll") for (int rt_ = 0; rt_ < 2; ++rt_)                        \
    _Pragma("unroll") for (int jt_ = 0; jt_ < 4; ++jt_)                        \
        C[rt_][jt_] = (f32x4){0.f, 0.f, 0.f, 0.f};                             \
    _Pragma("unroll") for (int kb_ = 0; kb_ < 8; ++kb_) {                      \
      _Pragma("unroll") for (int jt_ = 0; jt_ < 4; ++jt_) {                    \
        u32x2 bv_ = *reinterpret_cast<const u32x2*>(                           \
            sb_ + jt_ * 4096 + ((((kb_ << 1) | g2) ^ cx) << 4));               \
        long bl_ = __builtin_bit_cast(long, bv_);                              \
        C[0][jt_] = __builtin_amdgcn_mfma_f32_16x16x32_fp8_fp8(                \
            __builtin_bit_cast(long, a[0][kb_]), bl_, C[0][jt_], 0, 0, 0);     \
        C[1][jt_] = __builtin_amdgcn_mfma_f32_16x16x32_fp8_fp8(                \
            __builtin_bit_cast(long, a[1][kb_]), bl_, C[1][jt_], 0, 0, 0);     \
      }                                                                        \
    }                                                                          \
  } while (0)

  // branchless grouped online-lse fold of acc set F (one basic block)
#define FOLD(F)                                                                \
  do {                                                                         \
    _Pragma("unroll") for (int rt_ = 0; rt_ < 2; ++rt_)                        \
    _Pragma("unroll") for (int r_ = 0; r_ < 4; ++r_) {                         \
      float v0_ = F[rt_][0][r_], v1_ = F[rt_][1][r_];                          \
      float v2_ = F[rt_][2][r_], v3_ = F[rt_][3][r_];                          \
      float tm_ = fmaxf(fmaxf(v0_, v1_), fmaxf(v2_, v3_));                     \
      float mo_ = m[rt_][r_];                                                  \
      float mn_ = fmaxf(mo_, tm_);                                             \
      float sc_ = fexp2(mo_ - mn_);                                            \
      s[rt_][r_] = s[rt_][r_] * sc_ +                                          \
                   (fexp2(v0_ - mn_) + fexp2(v1_ - mn_) +                      \
                    fexp2(v2_ - mn_) + fexp2(v3_ - mn_));                      \
      m[rt_][r_] = mn_;                                                        \
    }                                                                          \
  } while (0)

  // ---- prologue: tile 0 -> accA (no fold yet)
  STAGE(0, 0);
  STAGE(1, 1);
  asm volatile("s_waitcnt vmcnt(4)" ::: "memory");
  __builtin_amdgcn_s_barrier();
  MFMA_TILE(0, accA);
  asm volatile("s_waitcnt lgkmcnt(0)" ::: "memory");
  __builtin_amdgcn_s_barrier();

  // ---- main loop: tiles 1..NT-2 in pairs (NT=16: tt = 1,3,...,13)
#pragma unroll 1
  for (int tt = 1; tt + 1 < NT; tt += 2) {
    // tile tt (buf1) -> accB; fold accA (tile tt-1) overlaps the vmcnt wait
    STAGE(0, tt + 1);
    FOLD(accA);
    asm volatile("s_waitcnt vmcnt(4)" ::: "memory");
    __builtin_amdgcn_s_barrier();
    MFMA_TILE(1, accB);
    asm volatile("s_waitcnt lgkmcnt(0)" ::: "memory");
    __builtin_amdgcn_s_barrier();

    // tile tt+1 (buf0) -> accA; fold accB (tile tt)
    STAGE(1, tt + 2);
    FOLD(accB);
    asm volatile("s_waitcnt vmcnt(4)" ::: "memory");
    __builtin_amdgcn_s_barrier();
    MFMA_TILE(0, accA);
    asm volatile("s_waitcnt lgkmcnt(0)" ::: "memory");
    __builtin_amdgcn_s_barrier();
  }

  // ---- epilogue: tile NT-1 (buf1) -> accB; folds of last two acc sets
  FOLD(accA);
  asm volatile("s_waitcnt vmcnt(0)" ::: "memory");
  __builtin_amdgcn_s_barrier();
  MFMA_TILE(1, accB);
  FOLD(accB);
#undef STAGE
#undef MFMA_TILE
#undef FOLD

  // merge the 16 lanes of each group (each held a 4-col-stride slice)
#pragma unroll
  for (int rt = 0; rt < 2; ++rt)
#pragma unroll
    for (int r = 0; r < 4; ++r) {
      float M = m[rt][r], S = s[rt][r];
#pragma unroll
      for (int off = 1; off < 16; off <<= 1) {
        float Mo = __shfl_xor(M, off);
        float So = __shfl_xor(S, off);
        float Mn = fmaxf(M, Mo);
        S = S * fexp2(M - Mn) + So * fexp2(Mo - Mn);
        M = Mn;
      }
      if (c == 0) {
        int row = qw + rt * 16 + g * 4 + r;
        pm[blockIdx.y * NQ + row] = M;
        ps[blockIdx.y * NQ + row] = S;
      }
    }
}

// ---------------------------------------------------------------------------
// Kernel 3: per-row lse (base-2 partials -> natural), block-sum -> part[64]
// ---------------------------------------------------------------------------
__global__ __launch_bounds__(128) void finalize1_kernel(
    const float* __restrict__ pm, const float* __restrict__ ps,
    float* __restrict__ part) {
  const int tid = threadIdx.x;
  const int row = blockIdx.x * 128 + tid;
  float M = -3.4e38f;
#pragma unroll
  for (int k = 0; k < NSPLIT; ++k) M = fmaxf(M, pm[k * NQ + row]);
  float S = 0.f;
#pragma unroll
  for (int k = 0; k < NSPLIT; ++k) S += ps[k * NQ + row] * fexp2(pm[k * NQ + row] - M);
  float v = LN2 * (M + flog2(S));

  __shared__ float red[128];
  red[tid] = v;
  __syncthreads();
#pragma unroll
  for (int st = 64; st > 0; st >>= 1) {
    if (tid < st) red[tid] += red[tid + st];
    __syncthreads();
  }
  if (tid == 0) part[blockIdx.x] = red[0];
}

// ---------------------------------------------------------------------------
// Kernel 4: sum 64 partials, negate.
// ---------------------------------------------------------------------------
__global__ __launch_bounds__(64) void finalize2_kernel(
    const float* __restrict__ part, float* __restrict__ out) {
  const int lane = threadIdx.x;
  float v = part[lane];
#pragma unroll
  for (int off = 1; off < 64; off <<= 1) v += __shfl_xor(v, off);
  if (lane == 0) out[0] = -v;
}

// ---------------------------------------------------------------------------
extern "C" void kernel_launch(void* const* d_in, const int* in_sizes, int n_in,
                              void* d_out, int out_size, void* d_ws, size_t ws_size,
                              hipStream_t stream) {
  const float* xq = (const float*)d_in[0];
  const float* xk = (const float*)d_in[1];
  const float* Wq = (const float*)d_in[2];
  const float* Wk = (const float*)d_in[3];

  char* ws = (char*)d_ws;
  // ws: Qb 2MB | Kb 2MB | pm 256KB | ps 256KB | part 256B
  uchar_t* Qb = (uchar_t*)(ws);
  uchar_t* Kb = (uchar_t*)(ws + (size_t)NQ * DD);
  float* pm = (float*)(ws + (size_t)(NQ + NK) * DD);
  float* ps = pm + (size_t)NSPLIT * NQ;
  float* part = ps + (size_t)NSPLIT * NQ;

  hipLaunchKernelGGL(proj_kernel, dim3(128, 2, 4), dim3(256), 0, stream,
                     xq, xk, Wq, Wk, Qb, Kb);
  hipLaunchKernelGGL(scores_lse_kernel, dim3(NQ / 128, NSPLIT), dim3(256), 0, stream,
                     Qb, Kb, pm, ps);
  hipLaunchKernelGGL(finalize1_kernel, dim3(64), dim3(128), 0, stream, pm, ps, part);
  hipLaunchKernelGGL(finalize2_kernel, dim3(1), dim3(64), 0, stream, part, (float*)d_out);
}